// Round 9
// baseline (433.679 us; speedup 1.0000x reference)
//
#include <hip/hip_runtime.h>
#include <stdint.h>

typedef unsigned short u16;
typedef short short8 __attribute__((ext_vector_type(8)));
typedef float f32x4 __attribute__((ext_vector_type(4)));
typedef u16 u16x4 __attribute__((ext_vector_type(4)));
typedef u16 u16x8 __attribute__((ext_vector_type(8)));

#define MODE_F32  0
#define MODE_GELU 2
#define MODE_VT   4

// 8 (bug-faithful sqrt(hd) scale) * log2(e): softmax runs in exp2 domain
#define QSCALE 11.5415603271f

__device__ __forceinline__ float b2f(u16 v) {
    union { uint32_t u; float f; } x; x.u = ((uint32_t)v) << 16; return x.f;
}
__device__ __forceinline__ u16 f2b(float f) {
    union { float f; uint32_t u; } x; x.f = f;
    uint32_t u = x.u;
    return (u16)((u + 0x7FFFu + ((u >> 16) & 1u)) >> 16);   // RNE
}
__device__ __forceinline__ u16 f2b_trunc(float f) {        // cheap: P only
    union { float f; uint32_t u; } x; x.f = f;
    return (u16)(x.u >> 16);
}

// async global->LDS, 16B per lane; LDS dest is wave-uniform base + lane*16
#define ASYNC16(gp, lp)                                                        \
    __builtin_amdgcn_global_load_lds(                                          \
        (const __attribute__((address_space(1))) uint32_t*)(const void*)(gp),  \
        (__attribute__((address_space(3))) uint32_t*)(void*)(lp), 16, 0, 0)

#define MFMA16(a, b, c) __builtin_amdgcn_mfma_f32_16x16x32_bf16((a), (b), (c), 0, 0, 0)

// ---------------------------------------------------------------------------
// fp32 -> (hi, lo) bf16 split
// ---------------------------------------------------------------------------
__global__ __launch_bounds__(256) void split_f32(
    const float* __restrict__ in, u16* __restrict__ hi, u16* __restrict__ lo)
{
    const int i = (blockIdx.x * 256 + threadIdx.x) * 4;
    f32x4 v = *(const f32x4*)&in[i];
    u16x4 h, l;
    for (int k = 0; k < 4; k++) {
        h[k] = f2b(v[k]);
        l[k] = f2b(v[k] - b2f(h[k]));
    }
    *(u16x4*)&hi[i] = h;
    *(u16x4*)&lo[i] = l;
}

// fp32 [rows,cols] -> bf16 [cols,rows] transpose+cast; z picks (inA,outA)/(inB,outB)
__global__ __launch_bounds__(256) void transpose_f32_bf16(
    const float* __restrict__ inA, u16* __restrict__ outA,
    const float* __restrict__ inB, u16* __restrict__ outB, int rows, int cols)
{
    const float* in = blockIdx.z ? inB : inA;
    u16* out = blockIdx.z ? outB : outA;
    __shared__ float t[32][33];
    const int r0 = blockIdx.y * 32, c0 = blockIdx.x * 32;
    const int tr = threadIdx.x >> 3, tc = (threadIdx.x & 7) * 4;
    f32x4 v = *(const f32x4*)&in[(size_t)(r0 + tr) * cols + c0 + tc];
    for (int i = 0; i < 4; i++) t[tr][tc + i] = v[i];
    __syncthreads();
    u16x4 ov;
    for (int i = 0; i < 4; i++) ov[i] = f2b(t[tc + i][tr]);
    *(u16x4*)&out[(size_t)(c0 + tr) * rows + r0 + tc] = ov;
}

// fp32 [rows,cols] -> bf16 hi/lo [cols,rows] transpose+split; z picks A/B set
__global__ __launch_bounds__(256) void transpose_split_f32(
    const float* __restrict__ inA, u16* __restrict__ hiA, u16* __restrict__ loA,
    const float* __restrict__ inB, u16* __restrict__ hiB, u16* __restrict__ loB,
    int rows, int cols)
{
    const float* in = blockIdx.z ? inB : inA;
    u16* hi = blockIdx.z ? hiB : hiA;
    u16* lo = blockIdx.z ? loB : loA;
    __shared__ float t[32][33];
    const int r0 = blockIdx.y * 32, c0 = blockIdx.x * 32;
    const int tr = threadIdx.x >> 3, tc = (threadIdx.x & 7) * 4;
    f32x4 v = *(const f32x4*)&in[(size_t)(r0 + tr) * cols + c0 + tc];
    for (int i = 0; i < 4; i++) t[tr][tc + i] = v[i];
    __syncthreads();
    u16x4 hv, lv;
    for (int i = 0; i < 4; i++) {
        const float f = t[tc + i][tr];
        hv[i] = f2b(f);
        lv[i] = f2b(f - b2f(hv[i]));
    }
    const size_t o = (size_t)(c0 + tr) * rows + r0 + tc;
    *(u16x4*)&hi[o] = hv;
    *(u16x4*)&lo[o] = lv;
}

// ---------------------------------------------------------------------------
// QK projection, bf16x3, dbuf, 8 waves/block (wave-tile 32x64, acc 2x4)
// Q output pre-scaled by QSCALE (8*log2e) for the exp2-domain softmax.
// ---------------------------------------------------------------------------
__global__ __launch_bounds__(512) void gemm_qk_x3(
    const u16* __restrict__ Ahi, const u16* __restrict__ Alo,
    const u16* __restrict__ Bhi, const u16* __restrict__ Blo,
    const float* __restrict__ bq, const float* __restrict__ bk,
    u16* __restrict__ Qhi, u16* __restrict__ Qlo,
    u16* __restrict__ Khi, u16* __restrict__ Klo)
{
    const int K = 1024;
    __shared__ __align__(16) u16 SM[32768];   // 64 KB: 4 operands x dbuf
    u16* lAh = SM;          u16* lAl = SM + 8192;
    u16* lBh = SM + 16384;  u16* lBl = SM + 24576;

    const int tid = threadIdx.x;
    const int w = tid >> 6, lane = tid & 63;
    const int lane15 = lane & 15, q = lane >> 4;
    const int tM = blockIdx.y * 128, tN = blockIdx.x * 128;
    const int m0 = (w >> 1) * 32, n0 = (w & 1) * 64;

    f32x4 acc[2][4];
    for (int i = 0; i < 2; i++)
        for (int j = 0; j < 4; j++)
            acc[i][j] = (f32x4){0.f, 0.f, 0.f, 0.f};

    const int srow = lane >> 2, sch = lane & 3;
    const u16* Ah = Ahi + (size_t)tM * K;
    const u16* Al = Alo + (size_t)tM * K;
    const u16* Bh = Bhi + (size_t)tN * K;
    const u16* Bl = Blo + (size_t)tN * K;
    // 32 staging chunks (4 operands x 8), 4 per wave: id = w*4+ii
    // id>>3 selects operand (Ah,Al,Bh,Bl), id&7 selects 16-row chunk

    #define STAGE_QK(buf_off, k0)                                              \
        for (int ii = 0; ii < 4; ii++) {                                       \
            const int id = w * 4 + ii, op = id >> 3, ch = id & 7;              \
            const u16* src = op == 0 ? Ah : op == 1 ? Al : op == 2 ? Bh : Bl;  \
            u16* dst = op == 0 ? lAh : op == 1 ? lAl : op == 2 ? lBh : lBl;    \
            ASYNC16(src + (size_t)(ch * 16 + srow) * K + (k0) + sch * 8,       \
                    dst + (buf_off) + ch * 512);                               \
        }

    STAGE_QK(0, 0)

    const int NT = K / 32;
    for (int kt = 0; kt < NT; kt++) {
        __syncthreads();
        const int cb = (kt & 1) * 4096, nb = 4096 - cb;
        if (kt + 1 < NT) {
            const int k0 = (kt + 1) * 32;
            STAGE_QK(nb, k0)
        }
        short8 afh[2], afl[2], bfh[4], bfl[4];
        for (int i = 0; i < 2; i++) {
            const int o = cb + (m0 + i * 16 + lane15) * 32 + q * 8;
            afh[i] = *(const short8*)&lAh[o];
            afl[i] = *(const short8*)&lAl[o];
        }
        for (int j = 0; j < 4; j++) {
            const int o = cb + (n0 + j * 16 + lane15) * 32 + q * 8;
            bfh[j] = *(const short8*)&lBh[o];
            bfl[j] = *(const short8*)&lBl[o];
        }
        for (int i = 0; i < 2; i++)
            for (int j = 0; j < 4; j++) {
                acc[i][j] = MFMA16(afh[i], bfh[j], acc[i][j]);
                acc[i][j] = MFMA16(afh[i], bfl[j], acc[i][j]);
                acc[i][j] = MFMA16(afl[i], bfh[j], acc[i][j]);
            }
    }

    // epilogue: Q (tN<1024, scaled) or K; hi+lo passes through LDS, vec8 stores
    const bool isQ = (tN < 1024);
    u16* dhi = isQ ? Qhi : Khi;
    u16* dlo = isQ ? Qlo : Klo;
    const int cN = isQ ? tN : (tN - 1024);
    const float scl = isQ ? QSCALE : 1.0f;
    u16* sC = SM;   // 128 x 136
    for (int pass = 0; pass < 2; pass++) {
        __syncthreads();
        for (int i = 0; i < 2; i++) {
            const int rl0 = m0 + i * 16 + q * 4;
            for (int j = 0; j < 4; j++) {
                const int cl = n0 + j * 16 + lane15;
                const float bv = isQ ? bq[cN + cl] : bk[cN + cl];
                for (int r = 0; r < 4; r++) {
                    const float v = (acc[i][j][r] + bv) * scl;
                    const u16 hv = f2b(v);
                    sC[(rl0 + r) * 136 + cl] = pass == 0 ? hv : f2b(v - b2f(hv));
                }
            }
        }
        __syncthreads();
        u16* dst = pass == 0 ? dhi : dlo;
        for (int t8 = 0; t8 < 4; t8++) {
            const int rl = t8 * 32 + (tid >> 4), cl = (tid & 15) * 8;
            *(u16x8*)&dst[(size_t)(tM + rl) * 1024 + cN + cl] = *(const u16x8*)&sC[rl * 136 + cl];
        }
    }
}

// ---------------------------------------------------------------------------
// C = A[M,K] * Bt[N,K]^T + bias; dbuf; 8 waves/block (wave-tile 32x64);
// optional split-K via gridDim.z
// ---------------------------------------------------------------------------
__global__ __launch_bounds__(512) void gemm_bt(
    const u16* __restrict__ A, const u16* __restrict__ Bt, const float* __restrict__ bias,
    int M, int N, int K, int mode,
    float* __restrict__ outF, u16* __restrict__ outB, size_t pstride)
{
    __shared__ __align__(16) u16 SM[17408];
    u16* lA = SM;
    u16* lB = SM + 8192;

    const int tid = threadIdx.x;
    const int w = tid >> 6, lane = tid & 63;
    const int lane15 = lane & 15, q = lane >> 4;
    const int tM = blockIdx.y * 128, tN = blockIdx.x * 128;
    const int m0 = (w >> 1) * 32, n0 = (w & 1) * 64;

    const int kchunk = K / gridDim.z;
    const int koff = blockIdx.z * kchunk;
    outF += (size_t)blockIdx.z * pstride;

    f32x4 acc[2][4];
    for (int i = 0; i < 2; i++)
        for (int j = 0; j < 4; j++)
            acc[i][j] = (f32x4){0.f, 0.f, 0.f, 0.f};

    const int srow = lane >> 2, sch = lane & 3;
    const u16* Abase = A + (size_t)tM * K + koff;
    const u16* Bbase = Bt + (size_t)tN * K + koff;
    // 16 staging chunks (A 0..7, B 8..15), 2 per wave
    #define STAGE_BT(buf_off, k0)                                              \
        for (int ii = 0; ii < 2; ii++) {                                       \
            const int id = w * 2 + ii;                                         \
            const u16* src = id < 8 ? Abase : Bbase;                           \
            u16* dst = id < 8 ? lA : lB;                                       \
            const int ch = id & 7;                                             \
            ASYNC16(src + (size_t)(ch * 16 + srow) * K + (k0) + sch * 8,       \
                    dst + (buf_off) + ch * 512);                               \
        }

    STAGE_BT(0, 0)

    const int NT = kchunk / 32;
    for (int kt = 0; kt < NT; kt++) {
        __syncthreads();
        const int cb = (kt & 1) * 4096, nb = 4096 - cb;
        if (kt + 1 < NT) {
            const int k0 = (kt + 1) * 32;
            STAGE_BT(nb, k0)
        }
        short8 af[2], bf[4];
        for (int i = 0; i < 2; i++) af[i] = *(const short8*)&lA[cb + (m0 + i * 16 + lane15) * 32 + q * 8];
        for (int j = 0; j < 4; j++) bf[j] = *(const short8*)&lB[cb + (n0 + j * 16 + lane15) * 32 + q * 8];
        for (int i = 0; i < 2; i++)
            for (int j = 0; j < 4; j++)
                acc[i][j] = MFMA16(af[i], bf[j], acc[i][j]);
    }

    if (mode == MODE_F32) {
        for (int i = 0; i < 2; i++) {
            const int rb = tM + m0 + i * 16 + q * 4;
            for (int j = 0; j < 4; j++) {
                const int col = tN + n0 + j * 16 + lane15;
                const float bv = (bias && blockIdx.z == 0) ? bias[col] : 0.f;
                for (int r = 0; r < 4; r++)
                    outF[(size_t)(rb + r) * N + col] = acc[i][j][r] + bv;
            }
        }
        return;
    }

    u16* sC = SM;   // 128 x 136
    __syncthreads();
    if (mode == MODE_GELU) {
        for (int i = 0; i < 2; i++) {
            const int rl0 = m0 + i * 16 + q * 4;
            for (int j = 0; j < 4; j++) {
                const int cl = n0 + j * 16 + lane15;
                const float bv = bias[tN + cl];
                for (int r = 0; r < 4; r++) {
                    float v = acc[i][j][r] + bv;
                    v = 0.5f * v * (1.f + erff(v * 0.70710678118f));
                    sC[(rl0 + r) * 136 + cl] = f2b(v);
                }
            }
        }
        __syncthreads();
        for (int t8 = 0; t8 < 4; t8++) {
            const int rl = t8 * 32 + (tid >> 4), cl = (tid & 15) * 8;
            *(u16x8*)&outB[(size_t)(tM + rl) * N + tN + cl] = *(const u16x8*)&sC[rl * 136 + cl];
        }
    } else {  // MODE_VT
        for (int i = 0; i < 2; i++) {
            const int rl0 = m0 + i * 16 + q * 4;
            for (int j = 0; j < 4; j++) {
                const int cl = n0 + j * 16 + lane15;
                const float bv = bias[tN + cl];
                for (int r = 0; r < 4; r++)
                    sC[cl * 136 + rl0 + r] = f2b(acc[i][j][r] + bv);
            }
        }
        __syncthreads();
        const int bb = tM >> 11, nbase = tM & 2047;
        for (int t8 = 0; t8 < 4; t8++) {
            const int cl = t8 * 32 + (tid >> 4), rl = (tid & 15) * 8;
            const int colg = tN + cl;
            u16* dst = &outB[((size_t)(bb * 16 + (colg >> 6)) * 64 + (colg & 63)) * 2048 + nbase + rl];
            *(u16x8*)dst = *(const u16x8*)&sC[cl * 136 + rl];
        }
    }
}

// ---------------------------------------------------------------------------
// Flash attention v5: 512 threads / 8 waves; waves 0-3 own q-tile 2*k2,
// waves 4-7 own 2*k2+1 CONCURRENTLY (adjacent pairing: lower waves idle only
// 1 tile -> ~94% slot utilization). Block-level compute balance via the
// co-residency mapping u=blockIdx>>5, k2 = u<8 ? u : 23-u: blocks b and
// b+256 (same CU under round-robin dispatch) get k2=j and 15-j -> per-CU
// compute = 264 wave-tiles (constant) and walked tiles = 36 (vs 42-56 in
// v4). KVBLK=64, XOR-swizzled tiles, Q in registers, defer-max. Grid 512.
// ---------------------------------------------------------------------------
__global__ __launch_bounds__(512) void attn_fwd(
    const u16* __restrict__ Qhig, const u16* __restrict__ Qlog,
    const u16* __restrict__ Khig, const u16* __restrict__ Klog,
    const u16* __restrict__ Vtg, u16* __restrict__ Og)
{
    // K: [buf][64 keys][64 d], byte ^= (key&7)<<4 ; V: [buf][64 d][64 keys],
    // byte ^= (d&7)<<4. Both staged linearly by ASYNC16 with inverse-swizzled
    // global source (rule: linear dest + inv-swz source + swz read).
    __shared__ __align__(16) u16 lKh[2][4096];
    __shared__ __align__(16) u16 lKl[2][4096];
    __shared__ __align__(16) u16 lV [2][4096];
    __shared__ __align__(16) u16 lPb[8][1152];   // per-wave P: 16 rows x 72

    const int tid = threadIdx.x, w = tid >> 6, lane = tid & 63;
    const int lane15 = lane & 15, q = lane >> 4;
    const int bh = blockIdx.x & 31;              // same bh -> same XCD (mod 8)
    const int u = blockIdx.x >> 5;               // 0..15
    const int k2 = (u < 8) ? u : 23 - u;         // pair (j, 15-j) per CU
    const int b = bh >> 4, h = bh & 15;

    const size_t xoff = (size_t)b * 2048 * 1024 + h * 64;
    const u16* Qh_ = Qhig + xoff;
    const u16* Ql_ = Qlog + xoff;
    const u16* Kh_ = Khig + xoff;
    const u16* Kl_ = Klog + xoff;
    const u16* Vbh = Vtg + (size_t)bh * 64 * 2048;
    u16* Obh = Og + xoff;

    u16* lP = lPb[w];
    const float NEG = -3.0e38f;
    const float THR = 11.5415603271f;            // nat-8 in exp2 domain

    const int rsub = lane >> 3;                  // staging: row within 8-row chunk
    const int csw  = ((lane & 7) ^ rsub) * 8;    // staging: inv-swizzled col (elems)
    const int swz  = (lane15 & 7) << 3;          // read-side XOR (u16 units)

    short8 ones;
    for (int i = 0; i < 8; i++) ones[i] = (short)0x3F80;   // bf16 1.0 splat

    // 24 staging chunks/tile (Khi 0-7, Klo 8-15, V 16-23), 3 per wave
#define STAGE_KV(buf, k0)                                                      \
    for (int ii = 0; ii < 3; ii++) {                                           \
        const int id = w * 3 + ii, sel = id >> 3, c = id & 7;                  \
        if (sel == 0)                                                          \
            ASYNC16(Kh_ + (size_t)((k0) + c * 8 + rsub) * 1024 + csw,          \
                    &lKh[buf][c * 512]);                                       \
        else if (sel == 1)                                                     \
            ASYNC16(Kl_ + (size_t)((k0) + c * 8 + rsub) * 1024 + csw,          \
                    &lKl[buf][c * 512]);                                       \
        else                                                                   \
            ASYNC16(Vbh + (size_t)(c * 8 + rsub) * 2048 + (k0) + csw,          \
                    &lV[buf][c * 512]);                                        \
    }

    const int qb = 2 * k2 + (w >> 2);            // this wave-group's q-tile
    const int qrow0 = qb * 64;
    const int wrow0 = qrow0 + (w & 3) * 16;      // this wave's first query row
    const int ntiles = 2 * k2 + 2;               // tiles walked by the block

    // Q fragments straight from global (already scaled by QSCALE)
    const size_t qro = (size_t)(wrow0 + lane15) * 1024;
    short8 aqh0 = *(const short8*)&Qh_[qro + q * 8];
    short8 aqh1 = *(const short8*)&Qh_[qro + 32 + q * 8];
    short8 aql0 = *(const short8*)&Ql_[qro + q * 8];
    short8 aql1 = *(const short8*)&Ql_[qro + 32 + q * 8];

    STAGE_KV(0, 0)

    f32x4 o[4];
    for (int j = 0; j < 4; j++) o[j] = (f32x4){0.f, 0.f, 0.f, 0.f};
    float mrow[4], lrow[4];
    for (int r = 0; r < 4; r++) { mrow[r] = NEG; lrow[r] = 0.f; }

    for (int t = 0; t < ntiles; t++) {
        __syncthreads();   // tile t staged; prev-tile reads complete
        const int cur = t & 1, nxt = cur ^ 1;
        if (t + 1 < ntiles) {
            STAGE_KV(nxt, (t + 1) * 64)
        }
        const int kk0 = t * 64;
        if (kk0 > wrow0 + 15) continue;   // fully-masked tile (wave-uniform)

        // S = (Qhi+Qlo)(Khi+Klo)^T (lo*lo dropped); logits already *8*log2e
        f32x4 s[4];
        for (int sub = 0; sub < 4; sub++) {
            const int kb = (sub * 16 + lane15) * 64;
            short8 bkh0 = *(const short8*)&lKh[cur][kb + ((q * 8) ^ swz)];
            short8 bkh1 = *(const short8*)&lKh[cur][kb + ((32 + q * 8) ^ swz)];
            short8 bkl0 = *(const short8*)&lKl[cur][kb + ((q * 8) ^ swz)];
            short8 bkl1 = *(const short8*)&lKl[cur][kb + ((32 + q * 8) ^ swz)];
            f32x4 z = (f32x4){0.f, 0.f, 0.f, 0.f};
            z = MFMA16(aqh0, bkh0, z);
            z = MFMA16(aqh1, bkh1, z);
            z = MFMA16(aqh0, bkl0, z);
            z = MFMA16(aqh1, bkl1, z);
            z = MFMA16(aql0, bkh0, z);
            z = MFMA16(aql1, bkh1, z);
            s[sub] = z;
        }
        // causal mask: only this wave's diagonal tile needs it (uniform)
        if (kk0 + 63 > wrow0) {
            const int rbase = wrow0 + q * 4;
            for (int sub = 0; sub < 4; sub++)
                for (int r = 0; r < 4; r++) {
                    const int key = kk0 + sub * 16 + lane15;
                    if (key > rbase + r) s[sub][r] = NEG;
                }
        }
        // online softmax max (rows live in 16-lane groups)
        float mx[4];
        for (int r = 0; r < 4; r++)
            mx[r] = fmaxf(fmaxf(s[0][r], s[1][r]), fmaxf(s[2][r], s[3][r]));
        for (int d = 1; d < 16; d <<= 1)
            for (int r = 0; r < 4; r++) mx[r] = fmaxf(mx[r], __shfl_xor(mx[r], d));
        // defer-max: only rescale when max grew by > THR (P <= 2^THR)
        bool need = false;
        for (int r = 0; r < 4; r++) need |= (mx[r] > mrow[r] + THR);
        if (__any(need)) {
            for (int r = 0; r < 4; r++) {
                const float mnew = fmaxf(mrow[r], mx[r]);
                const float alpha = __builtin_exp2f(mrow[r] - mnew);
                mrow[r] = mnew;
                lrow[r] *= alpha;
                for (int j = 0; j < 4; j++) o[j][r] *= alpha;
            }
        }
        // P (truncating bf16; numerator & denominator use identical values)
        for (int sub = 0; sub < 4; sub++)
            for (int r = 0; r < 4; r++) {
                const float pv = __builtin_exp2f(s[sub][r] - mrow[r]);
                lP[(q * 4 + r) * 72 + sub * 16 + lane15] = f2b_trunc(pv);
            }
        short8 ap0 = *(const short8*)&lP[lane15 * 72 + q * 8];
        short8 ap1 = *(const short8*)&lP[lane15 * 72 + 32 + q * 8];
        // row-sum via ones-MFMA
        f32x4 zs = (f32x4){0.f, 0.f, 0.f, 0.f};
        zs = MFMA16(ap0, ones, zs);
        zs = MFMA16(ap1, ones, zs);
        for (int r = 0; r < 4; r++) lrow[r] += zs[r];
        // O += P V
        for (int j = 0; j < 4; j++) {
            const int vb = (j * 16 + lane15) * 64;
            short8 bv0 = *(const short8*)&lV[cur][vb + ((q * 8) ^ swz)];
            short8 bv1 = *(const short8*)&lV[cur][vb + ((32 + q * 8) ^ swz)];
            o[j] = MFMA16(ap0, bv0, o[j]);
            o[j] = MFMA16(ap1, bv1, o[j]);
        }
    }
    // normalize + write
    float inv[4];
    for (int r = 0; r < 4; r++) inv[r] = 1.0f / lrow[r];
    for (int j = 0; j < 4; j++)
        for (int r = 0; r < 4; r++)
            Obh[(size_t)(wrow0 + q * 4 + r) * 1024 + j * 16 + lane15] =
                f2b(o[j][r] * inv[r]);
#undef STAGE_KV
}

// ---------------------------------------------------------------------------
// y = LN(Xa [+Xb])*g + b + res; res fp32 or bf16; out bf16 and/or fp32
// ---------------------------------------------------------------------------
__global__ __launch_bounds__(256) void ln_res(
    const float* __restrict__ Xa, const float* __restrict__ Xb,
    const float* __restrict__ resF, const u16* __restrict__ resB,
    const float* __restrict__ g, const float* __restrict__ bb,
    u16* __restrict__ outB, float* __restrict__ outF)
{
    const int w = threadIdx.x >> 6, lane = threadIdx.x & 63;
    const int row = blockIdx.x * 4 + w;
    const size_t rowo = (size_t)row * 1024;
    f32x4 v[4];
    float s = 0.f, ss = 0.f;
    for (int i = 0; i < 4; i++) {
        const int c0 = (i * 64 + lane) * 4;
        v[i] = *(const f32x4*)&Xa[rowo + c0];
        if (Xb) {
            f32x4 v2 = *(const f32x4*)&Xb[rowo + c0];
            for (int k = 0; k < 4; k++) v[i][k] += v2[k];
        }
        for (int k = 0; k < 4; k++) { s += v[i][k]; ss += v[i][k] * v[i][k]; }
    }
    for (int d = 1; d < 64; d <<= 1) { s += __shfl_xor(s, d); ss += __shfl_xor(ss, d); }
    const float mu = s * (1.f / 1024.f);
    const float var = ss * (1.f / 1024.f) - mu * mu;
    const float rstd = rsqrtf(var + 1e-5f);
    for (int i = 0; i < 4; i++) {
        const int c0 = (i * 64 + lane) * 4;
        f32x4 gv = *(const f32x4*)&g[c0];
        f32x4 bv = *(const f32x4*)&bb[c0];
        f32x4 rv;
        if (resF) rv = *(const f32x4*)&resF[rowo + c0];
        else {
            u16x4 rb = *(const u16x4*)&resB[rowo + c0];
            for (int k = 0; k < 4; k++) rv[k] = b2f(rb[k]);
        }
        f32x4 ov;
        for (int k = 0; k < 4; k++)
            ov[k] = (v[i][k] - mu) * rstd * gv[k] + bv[k] + rv[k];
        if (outF) *(f32x4*)&outF[rowo + c0] = ov;
        if (outB) {
            u16x4 ob;
            for (int k = 0; k < 4; k++) ob[k] = f2b(ov[k]);
            *(u16x4*)&outB[rowo + c0] = ob;
        }
    }
}

// ---------------------------------------------------------------------------
extern "C" void kernel_launch(void* const* d_in, const int* in_sizes, int n_in,
                              void* d_out, int out_size, void* d_ws, size_t ws_size,
                              hipStream_t stream)
{
    const float* x   = (const float*)d_in[0];
    const float* Wq  = (const float*)d_in[1];  const float* bq  = (const float*)d_in[2];
    const float* Wk  = (const float*)d_in[3];  const float* bk  = (const float*)d_in[4];
    const float* Wv  = (const float*)d_in[5];  const float* bv  = (const float*)d_in[6];
    const float* Wo  = (const float*)d_in[7];  const float* bo  = (const float*)d_in[8];
    const float* g1  = (const float*)d_in[9];  const float* b1  = (const float*)d_in[10];
    const float* W1  = (const float*)d_in[11]; const float* bm1 = (const float*)d_in[12];
    const float* W2  = (const float*)d_in[13]; const float* bm2 = (const float*)d_in[14];
    const float* g2  = (const float*)d_in[15]; const float* b2  = (const float*)d_in[16];

    // workspace (88 MB peak, lifetime-aliased); MB = 1 MiB
    const size_t MB = (size_t)1 << 20;
    char* ws = (char*)d_ws;
    u16* xhi    = (u16*)(ws + 0 * MB);
    u16* xlo    = (u16*)(ws + 8 * MB);
    u16* WqkThi = (u16*)(ws + 16 * MB);
    u16* WqkTlo = (u16*)(ws + 20 * MB);
    u16* WvT    = (u16*)(ws + 24 * MB);
    u16* WoT    = (u16*)(ws + 26 * MB);
    u16* W1T    = (u16*)(ws + 32 * MB);
    u16* W2T    = (u16*)(ws + 40 * MB);
    u16* Qhi    = (u16*)(ws + 48 * MB);
    u16* Qlo    = (u16*)(ws + 56 * MB);
    u16* Khi    = (u16*)(ws + 64 * MB);
    u16* Klo    = (u16*)(ws + 72 * MB);
    u16* Vtb    = (u16*)(ws + 80 * MB);
    u16* aout   = (u16*)(ws + 16 * MB);
    float* O1   = (float*)(ws + 48 * MB);
    float* O2   = (float*)(ws + 64 * MB);
    u16* x1b    = (u16*)(ws + 80 * MB);
    u16* Hb     = (u16*)(ws + 0 * MB);
    float* H2a  = (float*)(ws + 48 * MB);
    float* H2b  = (float*)(ws + 64 * MB);

    split_f32<<<4096, 256, 0, stream>>>(x, xhi, xlo);
    transpose_split_f32<<<dim3(32, 32, 2), 256, 0, stream>>>(
        Wq, WqkThi, WqkTlo,
        Wk, WqkThi + 1024 * 1024, WqkTlo + 1024 * 1024, 1024, 1024);
    transpose_f32_bf16<<<dim3(32, 32, 2), 256, 0, stream>>>(Wv, WvT, Wo, WoT, 1024, 1024);
    transpose_f32_bf16<<<dim3(128, 32), 256, 0, stream>>>(W1, W1T, nullptr, nullptr, 1024, 4096);
    transpose_f32_bf16<<<dim3(32, 128), 256, 0, stream>>>(W2, W2T, nullptr, nullptr, 4096, 1024);

    gemm_qk_x3<<<dim3(16, 32), 512, 0, stream>>>(xhi, xlo, WqkThi, WqkTlo, bq, bk,
                                                 Qhi, Qlo, Khi, Klo);
    gemm_bt<<<dim3(8, 32), 512, 0, stream>>>(xhi, WvT, bv, 4096, 1024, 1024,
                                             MODE_VT, nullptr, Vtb, 0);

    attn_fwd<<<dim3(512), 512, 0, stream>>>(Qhi, Qlo, Khi, Klo, Vtb, aout);

    gemm_bt<<<dim3(8, 32, 2), 512, 0, stream>>>(aout, WoT, bo, 4096, 1024, 1024,
                                                MODE_F32, O1, nullptr, (size_t)16 * MB / 4);
    ln_res<<<1024, 256, 0, stream>>>(O1, O2, x, nullptr, g1, b1, x1b, nullptr);

    gemm_bt<<<dim3(32, 32), 512, 0, stream>>>(x1b, W1T, bm1, 4096, 4096, 1024,
                                              MODE_GELU, nullptr, Hb, 0);
    gemm_bt<<<dim3(8, 32, 2), 512, 0, stream>>>(Hb, W2T, bm2, 4096, 1024, 4096,
                                                MODE_F32, H2a, nullptr, (size_t)16 * MB / 4);
    ln_res<<<1024, 256, 0, stream>>>(H2a, H2b, nullptr, x1b, g2, b2, nullptr, (float*)d_out);
}

// Round 10
// 411.017 us; speedup vs baseline: 1.0551x; 1.0551x over previous
//
#include <hip/hip_runtime.h>
#include <stdint.h>

typedef unsigned short u16;
typedef short short8 __attribute__((ext_vector_type(8)));
typedef float f32x4 __attribute__((ext_vector_type(4)));
typedef u16 u16x4 __attribute__((ext_vector_type(4)));
typedef u16 u16x8 __attribute__((ext_vector_type(8)));

#define MODE_F32  0
#define MODE_GELU 2
#define MODE_VT   4

// 8 (bug-faithful sqrt(hd) scale) * log2(e): softmax runs in exp2 domain
#define QSCALE 11.5415603271f

__device__ __forceinline__ float b2f(u16 v) {
    union { uint32_t u; float f; } x; x.u = ((uint32_t)v) << 16; return x.f;
}
__device__ __forceinline__ u16 f2b(float f) {
    union { float f; uint32_t u; } x; x.f = f;
    uint32_t u = x.u;
    return (u16)((u + 0x7FFFu + ((u >> 16) & 1u)) >> 16);   // RNE
}
__device__ __forceinline__ u16 f2b_trunc(float f) {        // cheap: P only
    union { float f; uint32_t u; } x; x.f = f;
    return (u16)(x.u >> 16);
}

// async global->LDS, 16B per lane; LDS dest is wave-uniform base + lane*16
#define ASYNC16(gp, lp)                                                        \
    __builtin_amdgcn_global_load_lds(                                          \
        (const __attribute__((address_space(1))) uint32_t*)(const void*)(gp),  \
        (__attribute__((address_space(3))) uint32_t*)(void*)(lp), 16, 0, 0)

#define MFMA16(a, b, c) __builtin_amdgcn_mfma_f32_16x16x32_bf16((a), (b), (c), 0, 0, 0)

// ---------------------------------------------------------------------------
// fp32 -> (hi, lo) bf16 split
// ---------------------------------------------------------------------------
__global__ __launch_bounds__(256) void split_f32(
    const float* __restrict__ in, u16* __restrict__ hi, u16* __restrict__ lo)
{
    const int i = (blockIdx.x * 256 + threadIdx.x) * 4;
    f32x4 v = *(const f32x4*)&in[i];
    u16x4 h, l;
    for (int k = 0; k < 4; k++) {
        h[k] = f2b(v[k]);
        l[k] = f2b(v[k] - b2f(h[k]));
    }
    *(u16x4*)&hi[i] = h;
    *(u16x4*)&lo[i] = l;
}

// fp32 [rows,cols] -> bf16 [cols,rows] transpose+cast; z picks (inA,outA)/(inB,outB)
__global__ __launch_bounds__(256) void transpose_f32_bf16(
    const float* __restrict__ inA, u16* __restrict__ outA,
    const float* __restrict__ inB, u16* __restrict__ outB, int rows, int cols)
{
    const float* in = blockIdx.z ? inB : inA;
    u16* out = blockIdx.z ? outB : outA;
    __shared__ float t[32][33];
    const int r0 = blockIdx.y * 32, c0 = blockIdx.x * 32;
    const int tr = threadIdx.x >> 3, tc = (threadIdx.x & 7) * 4;
    f32x4 v = *(const f32x4*)&in[(size_t)(r0 + tr) * cols + c0 + tc];
    for (int i = 0; i < 4; i++) t[tr][tc + i] = v[i];
    __syncthreads();
    u16x4 ov;
    for (int i = 0; i < 4; i++) ov[i] = f2b(t[tc + i][tr]);
    *(u16x4*)&out[(size_t)(c0 + tr) * rows + r0 + tc] = ov;
}

// fp32 [rows,cols] -> bf16 hi/lo [cols,rows] transpose+split; z picks A/B set
__global__ __launch_bounds__(256) void transpose_split_f32(
    const float* __restrict__ inA, u16* __restrict__ hiA, u16* __restrict__ loA,
    const float* __restrict__ inB, u16* __restrict__ hiB, u16* __restrict__ loB,
    int rows, int cols)
{
    const float* in = blockIdx.z ? inB : inA;
    u16* hi = blockIdx.z ? hiB : hiA;
    u16* lo = blockIdx.z ? loB : loA;
    __shared__ float t[32][33];
    const int r0 = blockIdx.y * 32, c0 = blockIdx.x * 32;
    const int tr = threadIdx.x >> 3, tc = (threadIdx.x & 7) * 4;
    f32x4 v = *(const f32x4*)&in[(size_t)(r0 + tr) * cols + c0 + tc];
    for (int i = 0; i < 4; i++) t[tr][tc + i] = v[i];
    __syncthreads();
    u16x4 hv, lv;
    for (int i = 0; i < 4; i++) {
        const float f = t[tc + i][tr];
        hv[i] = f2b(f);
        lv[i] = f2b(f - b2f(hv[i]));
    }
    const size_t o = (size_t)(c0 + tr) * rows + r0 + tc;
    *(u16x4*)&hi[o] = hv;
    *(u16x4*)&lo[o] = lv;
}

// ---------------------------------------------------------------------------
// QK projection, bf16x3, dbuf, 8 waves/block (wave-tile 32x64, acc 2x4)
// Q output pre-scaled by QSCALE (8*log2e) for the exp2-domain softmax.
// ---------------------------------------------------------------------------
__global__ __launch_bounds__(512) void gemm_qk_x3(
    const u16* __restrict__ Ahi, const u16* __restrict__ Alo,
    const u16* __restrict__ Bhi, const u16* __restrict__ Blo,
    const float* __restrict__ bq, const float* __restrict__ bk,
    u16* __restrict__ Qhi, u16* __restrict__ Qlo,
    u16* __restrict__ Khi, u16* __restrict__ Klo)
{
    const int K = 1024;
    __shared__ __align__(16) u16 SM[32768];   // 64 KB: 4 operands x dbuf
    u16* lAh = SM;          u16* lAl = SM + 8192;
    u16* lBh = SM + 16384;  u16* lBl = SM + 24576;

    const int tid = threadIdx.x;
    const int w = tid >> 6, lane = tid & 63;
    const int lane15 = lane & 15, q = lane >> 4;
    const int tM = blockIdx.y * 128, tN = blockIdx.x * 128;
    const int m0 = (w >> 1) * 32, n0 = (w & 1) * 64;

    f32x4 acc[2][4];
    for (int i = 0; i < 2; i++)
        for (int j = 0; j < 4; j++)
            acc[i][j] = (f32x4){0.f, 0.f, 0.f, 0.f};

    const int srow = lane >> 2, sch = lane & 3;
    const u16* Ah = Ahi + (size_t)tM * K;
    const u16* Al = Alo + (size_t)tM * K;
    const u16* Bh = Bhi + (size_t)tN * K;
    const u16* Bl = Blo + (size_t)tN * K;
    // 32 staging chunks (4 operands x 8), 4 per wave: id = w*4+ii
    // id>>3 selects operand (Ah,Al,Bh,Bl), id&7 selects 16-row chunk

    #define STAGE_QK(buf_off, k0)                                              \
        for (int ii = 0; ii < 4; ii++) {                                       \
            const int id = w * 4 + ii, op = id >> 3, ch = id & 7;              \
            const u16* src = op == 0 ? Ah : op == 1 ? Al : op == 2 ? Bh : Bl;  \
            u16* dst = op == 0 ? lAh : op == 1 ? lAl : op == 2 ? lBh : lBl;    \
            ASYNC16(src + (size_t)(ch * 16 + srow) * K + (k0) + sch * 8,       \
                    dst + (buf_off) + ch * 512);                               \
        }

    STAGE_QK(0, 0)

    const int NT = K / 32;
    for (int kt = 0; kt < NT; kt++) {
        __syncthreads();
        const int cb = (kt & 1) * 4096, nb = 4096 - cb;
        if (kt + 1 < NT) {
            const int k0 = (kt + 1) * 32;
            STAGE_QK(nb, k0)
        }
        short8 afh[2], afl[2], bfh[4], bfl[4];
        for (int i = 0; i < 2; i++) {
            const int o = cb + (m0 + i * 16 + lane15) * 32 + q * 8;
            afh[i] = *(const short8*)&lAh[o];
            afl[i] = *(const short8*)&lAl[o];
        }
        for (int j = 0; j < 4; j++) {
            const int o = cb + (n0 + j * 16 + lane15) * 32 + q * 8;
            bfh[j] = *(const short8*)&lBh[o];
            bfl[j] = *(const short8*)&lBl[o];
        }
        for (int i = 0; i < 2; i++)
            for (int j = 0; j < 4; j++) {
                acc[i][j] = MFMA16(afh[i], bfh[j], acc[i][j]);
                acc[i][j] = MFMA16(afh[i], bfl[j], acc[i][j]);
                acc[i][j] = MFMA16(afl[i], bfh[j], acc[i][j]);
            }
    }

    // epilogue: Q (tN<1024, scaled) or K; hi+lo passes through LDS, vec8 stores
    const bool isQ = (tN < 1024);
    u16* dhi = isQ ? Qhi : Khi;
    u16* dlo = isQ ? Qlo : Klo;
    const int cN = isQ ? tN : (tN - 1024);
    const float scl = isQ ? QSCALE : 1.0f;
    u16* sC = SM;   // 128 x 136
    for (int pass = 0; pass < 2; pass++) {
        __syncthreads();
        for (int i = 0; i < 2; i++) {
            const int rl0 = m0 + i * 16 + q * 4;
            for (int j = 0; j < 4; j++) {
                const int cl = n0 + j * 16 + lane15;
                const float bv = isQ ? bq[cN + cl] : bk[cN + cl];
                for (int r = 0; r < 4; r++) {
                    const float v = (acc[i][j][r] + bv) * scl;
                    const u16 hv = f2b(v);
                    sC[(rl0 + r) * 136 + cl] = pass == 0 ? hv : f2b(v - b2f(hv));
                }
            }
        }
        __syncthreads();
        u16* dst = pass == 0 ? dhi : dlo;
        for (int t8 = 0; t8 < 4; t8++) {
            const int rl = t8 * 32 + (tid >> 4), cl = (tid & 15) * 8;
            *(u16x8*)&dst[(size_t)(tM + rl) * 1024 + cN + cl] = *(const u16x8*)&sC[rl * 136 + cl];
        }
    }
}

// ---------------------------------------------------------------------------
// C = A[M,K] * Bt[N,K]^T + bias; dbuf; 8 waves/block (wave-tile 32x64);
// optional split-K via gridDim.z
// ---------------------------------------------------------------------------
__global__ __launch_bounds__(512) void gemm_bt(
    const u16* __restrict__ A, const u16* __restrict__ Bt, const float* __restrict__ bias,
    int M, int N, int K, int mode,
    float* __restrict__ outF, u16* __restrict__ outB, size_t pstride)
{
    __shared__ __align__(16) u16 SM[17408];
    u16* lA = SM;
    u16* lB = SM + 8192;

    const int tid = threadIdx.x;
    const int w = tid >> 6, lane = tid & 63;
    const int lane15 = lane & 15, q = lane >> 4;
    const int tM = blockIdx.y * 128, tN = blockIdx.x * 128;
    const int m0 = (w >> 1) * 32, n0 = (w & 1) * 64;

    const int kchunk = K / gridDim.z;
    const int koff = blockIdx.z * kchunk;
    outF += (size_t)blockIdx.z * pstride;

    f32x4 acc[2][4];
    for (int i = 0; i < 2; i++)
        for (int j = 0; j < 4; j++)
            acc[i][j] = (f32x4){0.f, 0.f, 0.f, 0.f};

    const int srow = lane >> 2, sch = lane & 3;
    const u16* Abase = A + (size_t)tM * K + koff;
    const u16* Bbase = Bt + (size_t)tN * K + koff;
    // 16 staging chunks (A 0..7, B 8..15), 2 per wave
    #define STAGE_BT(buf_off, k0)                                              \
        for (int ii = 0; ii < 2; ii++) {                                       \
            const int id = w * 2 + ii;                                         \
            const u16* src = id < 8 ? Abase : Bbase;                           \
            u16* dst = id < 8 ? lA : lB;                                       \
            const int ch = id & 7;                                             \
            ASYNC16(src + (size_t)(ch * 16 + srow) * K + (k0) + sch * 8,       \
                    dst + (buf_off) + ch * 512);                               \
        }

    STAGE_BT(0, 0)

    const int NT = kchunk / 32;
    for (int kt = 0; kt < NT; kt++) {
        __syncthreads();
        const int cb = (kt & 1) * 4096, nb = 4096 - cb;
        if (kt + 1 < NT) {
            const int k0 = (kt + 1) * 32;
            STAGE_BT(nb, k0)
        }
        short8 af[2], bf[4];
        for (int i = 0; i < 2; i++) af[i] = *(const short8*)&lA[cb + (m0 + i * 16 + lane15) * 32 + q * 8];
        for (int j = 0; j < 4; j++) bf[j] = *(const short8*)&lB[cb + (n0 + j * 16 + lane15) * 32 + q * 8];
        for (int i = 0; i < 2; i++)
            for (int j = 0; j < 4; j++)
                acc[i][j] = MFMA16(af[i], bf[j], acc[i][j]);
    }

    if (mode == MODE_F32) {
        for (int i = 0; i < 2; i++) {
            const int rb = tM + m0 + i * 16 + q * 4;
            for (int j = 0; j < 4; j++) {
                const int col = tN + n0 + j * 16 + lane15;
                const float bv = (bias && blockIdx.z == 0) ? bias[col] : 0.f;
                for (int r = 0; r < 4; r++)
                    outF[(size_t)(rb + r) * N + col] = acc[i][j][r] + bv;
            }
        }
        return;
    }

    u16* sC = SM;   // 128 x 136
    __syncthreads();
    if (mode == MODE_GELU) {
        for (int i = 0; i < 2; i++) {
            const int rl0 = m0 + i * 16 + q * 4;
            for (int j = 0; j < 4; j++) {
                const int cl = n0 + j * 16 + lane15;
                const float bv = bias[tN + cl];
                for (int r = 0; r < 4; r++) {
                    float v = acc[i][j][r] + bv;
                    v = 0.5f * v * (1.f + erff(v * 0.70710678118f));
                    sC[(rl0 + r) * 136 + cl] = f2b(v);
                }
            }
        }
        __syncthreads();
        for (int t8 = 0; t8 < 4; t8++) {
            const int rl = t8 * 32 + (tid >> 4), cl = (tid & 15) * 8;
            *(u16x8*)&outB[(size_t)(tM + rl) * N + tN + cl] = *(const u16x8*)&sC[rl * 136 + cl];
        }
    } else {  // MODE_VT
        for (int i = 0; i < 2; i++) {
            const int rl0 = m0 + i * 16 + q * 4;
            for (int j = 0; j < 4; j++) {
                const int cl = n0 + j * 16 + lane15;
                const float bv = bias[tN + cl];
                for (int r = 0; r < 4; r++)
                    sC[cl * 136 + rl0 + r] = f2b(acc[i][j][r] + bv);
            }
        }
        __syncthreads();
        const int bb = tM >> 11, nbase = tM & 2047;
        for (int t8 = 0; t8 < 4; t8++) {
            const int cl = t8 * 32 + (tid >> 4), rl = (tid & 15) * 8;
            const int colg = tN + cl;
            u16* dst = &outB[((size_t)(bb * 16 + (colg >> 6)) * 64 + (colg & 63)) * 2048 + nbase + rl];
            *(u16x8*)dst = *(const u16x8*)&sC[cl * 136 + rl];
        }
    }
}

// ---------------------------------------------------------------------------
// Flash attention v6 = v4 (R8 measured-best mapping) + T5 setprio around
// MFMA clusters. 512 threads / 8 waves; waves 0-3 own q-tile p, waves 4-7
// own 31-p concurrently, sharing staged K/V; per-block compute = 132
// wave-tiles (uniform); co-resident pair durations similar (32-p vs 24-p).
// KVBLK=64, XOR-swizzled tiles, Q in registers, defer-max. Grid 512.
// ---------------------------------------------------------------------------
__global__ __launch_bounds__(512) void attn_fwd(
    const u16* __restrict__ Qhig, const u16* __restrict__ Qlog,
    const u16* __restrict__ Khig, const u16* __restrict__ Klog,
    const u16* __restrict__ Vtg, u16* __restrict__ Og)
{
    // K: [buf][64 keys][64 d], byte ^= (key&7)<<4 ; V: [buf][64 d][64 keys],
    // byte ^= (d&7)<<4. Both staged linearly by ASYNC16 with inverse-swizzled
    // global source (rule: linear dest + inv-swz source + swz read).
    __shared__ __align__(16) u16 lKh[2][4096];
    __shared__ __align__(16) u16 lKl[2][4096];
    __shared__ __align__(16) u16 lV [2][4096];
    __shared__ __align__(16) u16 lPb[8][1152];   // per-wave P: 16 rows x 72

    const int tid = threadIdx.x, w = tid >> 6, lane = tid & 63;
    const int lane15 = lane & 15, q = lane >> 4;
    const int bh = blockIdx.x & 31;              // same bh -> same XCD (mod 8)
    const int p = blockIdx.x >> 5;               // 0..15; p=0 (longest) first
    const int b = bh >> 4, h = bh & 15;

    const size_t xoff = (size_t)b * 2048 * 1024 + h * 64;
    const u16* Qh_ = Qhig + xoff;
    const u16* Ql_ = Qlog + xoff;
    const u16* Kh_ = Khig + xoff;
    const u16* Kl_ = Klog + xoff;
    const u16* Vbh = Vtg + (size_t)bh * 64 * 2048;
    u16* Obh = Og + xoff;

    u16* lP = lPb[w];
    const float NEG = -3.0e38f;
    const float THR = 11.5415603271f;            // nat-8 in exp2 domain

    const int rsub = lane >> 3;                  // staging: row within 8-row chunk
    const int csw  = ((lane & 7) ^ rsub) * 8;    // staging: inv-swizzled col (elems)
    const int swz  = (lane15 & 7) << 3;          // read-side XOR (u16 units)

    short8 ones;
    for (int i = 0; i < 8; i++) ones[i] = (short)0x3F80;   // bf16 1.0 splat

    // 24 staging chunks/tile (Khi 0-7, Klo 8-15, V 16-23), 3 per wave
#define STAGE_KV(buf, k0)                                                      \
    for (int ii = 0; ii < 3; ii++) {                                           \
        const int id = w * 3 + ii, sel = id >> 3, c = id & 7;                  \
        if (sel == 0)                                                          \
            ASYNC16(Kh_ + (size_t)((k0) + c * 8 + rsub) * 1024 + csw,          \
                    &lKh[buf][c * 512]);                                       \
        else if (sel == 1)                                                     \
            ASYNC16(Kl_ + (size_t)((k0) + c * 8 + rsub) * 1024 + csw,          \
                    &lKl[buf][c * 512]);                                       \
        else                                                                   \
            ASYNC16(Vbh + (size_t)(c * 8 + rsub) * 2048 + (k0) + csw,          \
                    &lV[buf][c * 512]);                                        \
    }

    const int qb = (w < 4) ? p : (31 - p);       // this wave-group's q-tile
    const int qrow0 = qb * 64;
    const int wrow0 = qrow0 + (w & 3) * 16;      // this wave's first query row
    const int ntiles = 32 - p;                   // tiles walked by the block

    // Q fragments straight from global (already scaled by QSCALE)
    const size_t qro = (size_t)(wrow0 + lane15) * 1024;
    short8 aqh0 = *(const short8*)&Qh_[qro + q * 8];
    short8 aqh1 = *(const short8*)&Qh_[qro + 32 + q * 8];
    short8 aql0 = *(const short8*)&Ql_[qro + q * 8];
    short8 aql1 = *(const short8*)&Ql_[qro + 32 + q * 8];

    STAGE_KV(0, 0)

    f32x4 o[4];
    for (int j = 0; j < 4; j++) o[j] = (f32x4){0.f, 0.f, 0.f, 0.f};
    float mrow[4], lrow[4];
    for (int r = 0; r < 4; r++) { mrow[r] = NEG; lrow[r] = 0.f; }

    for (int t = 0; t < ntiles; t++) {
        __syncthreads();   // tile t staged; prev-tile reads complete
        const int cur = t & 1, nxt = cur ^ 1;
        if (t + 1 < ntiles) {
            STAGE_KV(nxt, (t + 1) * 64)
        }
        const int kk0 = t * 64;
        if (kk0 > wrow0 + 15) continue;   // fully-masked tile (wave-uniform)

        // S = (Qhi+Qlo)(Khi+Klo)^T (lo*lo dropped); logits already *8*log2e
        f32x4 s[4];
        __builtin_amdgcn_s_setprio(1);            // T5: favor MFMA-issuing wave
        for (int sub = 0; sub < 4; sub++) {
            const int kb = (sub * 16 + lane15) * 64;
            short8 bkh0 = *(const short8*)&lKh[cur][kb + ((q * 8) ^ swz)];
            short8 bkh1 = *(const short8*)&lKh[cur][kb + ((32 + q * 8) ^ swz)];
            short8 bkl0 = *(const short8*)&lKl[cur][kb + ((q * 8) ^ swz)];
            short8 bkl1 = *(const short8*)&lKl[cur][kb + ((32 + q * 8) ^ swz)];
            f32x4 z = (f32x4){0.f, 0.f, 0.f, 0.f};
            z = MFMA16(aqh0, bkh0, z);
            z = MFMA16(aqh1, bkh1, z);
            z = MFMA16(aqh0, bkl0, z);
            z = MFMA16(aqh1, bkl1, z);
            z = MFMA16(aql0, bkh0, z);
            z = MFMA16(aql1, bkh1, z);
            s[sub] = z;
        }
        __builtin_amdgcn_s_setprio(0);
        // causal mask: only this wave's diagonal tile needs it (uniform)
        if (kk0 + 63 > wrow0) {
            const int rbase = wrow0 + q * 4;
            for (int sub = 0; sub < 4; sub++)
                for (int r = 0; r < 4; r++) {
                    const int key = kk0 + sub * 16 + lane15;
                    if (key > rbase + r) s[sub][r] = NEG;
                }
        }
        // online softmax max (rows live in 16-lane groups)
        float mx[4];
        for (int r = 0; r < 4; r++)
            mx[r] = fmaxf(fmaxf(s[0][r], s[1][r]), fmaxf(s[2][r], s[3][r]));
        for (int d = 1; d < 16; d <<= 1)
            for (int r = 0; r < 4; r++) mx[r] = fmaxf(mx[r], __shfl_xor(mx[r], d));
        // defer-max: only rescale when max grew by > THR (P <= 2^THR)
        bool need = false;
        for (int r = 0; r < 4; r++) need |= (mx[r] > mrow[r] + THR);
        if (__any(need)) {
            for (int r = 0; r < 4; r++) {
                const float mnew = fmaxf(mrow[r], mx[r]);
                const float alpha = __builtin_exp2f(mrow[r] - mnew);
                mrow[r] = mnew;
                lrow[r] *= alpha;
                for (int j = 0; j < 4; j++) o[j][r] *= alpha;
            }
        }
        // P (truncating bf16; numerator & denominator use identical values)
        for (int sub = 0; sub < 4; sub++)
            for (int r = 0; r < 4; r++) {
                const float pv = __builtin_exp2f(s[sub][r] - mrow[r]);
                lP[(q * 4 + r) * 72 + sub * 16 + lane15] = f2b_trunc(pv);
            }
        short8 ap0 = *(const short8*)&lP[lane15 * 72 + q * 8];
        short8 ap1 = *(const short8*)&lP[lane15 * 72 + 32 + q * 8];
        // row-sum via ones-MFMA + O += P V
        __builtin_amdgcn_s_setprio(1);            // T5
        f32x4 zs = (f32x4){0.f, 0.f, 0.f, 0.f};
        zs = MFMA16(ap0, ones, zs);
        zs = MFMA16(ap1, ones, zs);
        for (int j = 0; j < 4; j++) {
            const int vb = (j * 16 + lane15) * 64;
            short8 bv0 = *(const short8*)&lV[cur][vb + ((q * 8) ^ swz)];
            short8 bv1 = *(const short8*)&lV[cur][vb + ((32 + q * 8) ^ swz)];
            o[j] = MFMA16(ap0, bv0, o[j]);
            o[j] = MFMA16(ap1, bv1, o[j]);
        }
        __builtin_amdgcn_s_setprio(0);
        for (int r = 0; r < 4; r++) lrow[r] += zs[r];
    }
    // normalize + write
    float inv[4];
    for (int r = 0; r < 4; r++) inv[r] = 1.0f / lrow[r];
    for (int j = 0; j < 4; j++)
        for (int r = 0; r < 4; r++)
            Obh[(size_t)(wrow0 + q * 4 + r) * 1024 + j * 16 + lane15] =
                f2b(o[j][r] * inv[r]);
#undef STAGE_KV
}

// ---------------------------------------------------------------------------
// y = LN(Xa [+Xb])*g + b + res; res fp32 or bf16; out bf16 and/or fp32
// ---------------------------------------------------------------------------
__global__ __launch_bounds__(256) void ln_res(
    const float* __restrict__ Xa, const float* __restrict__ Xb,
    const float* __restrict__ resF, const u16* __restrict__ resB,
    const float* __restrict__ g, const float* __restrict__ bb,
    u16* __restrict__ outB, float* __restrict__ outF)
{
    const int w = threadIdx.x >> 6, lane = threadIdx.x & 63;
    const int row = blockIdx.x * 4 + w;
    const size_t rowo = (size_t)row * 1024;
    f32x4 v[4];
    float s = 0.f, ss = 0.f;
    for (int i = 0; i < 4; i++) {
        const int c0 = (i * 64 + lane) * 4;
        v[i] = *(const f32x4*)&Xa[rowo + c0];
        if (Xb) {
            f32x4 v2 = *(const f32x4*)&Xb[rowo + c0];
            for (int k = 0; k < 4; k++) v[i][k] += v2[k];
        }
        for (int k = 0; k < 4; k++) { s += v[i][k]; ss += v[i][k] * v[i][k]; }
    }
    for (int d = 1; d < 64; d <<= 1) { s += __shfl_xor(s, d); ss += __shfl_xor(ss, d); }
    const float mu = s * (1.f / 1024.f);
    const float var = ss * (1.f / 1024.f) - mu * mu;
    const float rstd = rsqrtf(var + 1e-5f);
    for (int i = 0; i < 4; i++) {
        const int c0 = (i * 64 + lane) * 4;
        f32x4 gv = *(const f32x4*)&g[c0];
        f32x4 bv = *(const f32x4*)&bb[c0];
        f32x4 rv;
        if (resF) rv = *(const f32x4*)&resF[rowo + c0];
        else {
            u16x4 rb = *(const u16x4*)&resB[rowo + c0];
            for (int k = 0; k < 4; k++) rv[k] = b2f(rb[k]);
        }
        f32x4 ov;
        for (int k = 0; k < 4; k++)
            ov[k] = (v[i][k] - mu) * rstd * gv[k] + bv[k] + rv[k];
        if (outF) *(f32x4*)&outF[rowo + c0] = ov;
        if (outB) {
            u16x4 ob;
            for (int k = 0; k < 4; k++) ob[k] = f2b(ov[k]);
            *(u16x4*)&outB[rowo + c0] = ob;
        }
    }
}

// ---------------------------------------------------------------------------
extern "C" void kernel_launch(void* const* d_in, const int* in_sizes, int n_in,
                              void* d_out, int out_size, void* d_ws, size_t ws_size,
                              hipStream_t stream)
{
    const float* x   = (const float*)d_in[0];
    const float* Wq  = (const float*)d_in[1];  const float* bq  = (const float*)d_in[2];
    const float* Wk  = (const float*)d_in[3];  const float* bk  = (const float*)d_in[4];
    const float* Wv  = (const float*)d_in[5];  const float* bv  = (const float*)d_in[6];
    const float* Wo  = (const float*)d_in[7];  const float* bo  = (const float*)d_in[8];
    const float* g1  = (const float*)d_in[9];  const float* b1  = (const float*)d_in[10];
    const float* W1  = (const float*)d_in[11]; const float* bm1 = (const float*)d_in[12];
    const float* W2  = (const float*)d_in[13]; const float* bm2 = (const float*)d_in[14];
    const float* g2  = (const float*)d_in[15]; const float* b2  = (const float*)d_in[16];

    // workspace (88 MB peak, lifetime-aliased); MB = 1 MiB
    const size_t MB = (size_t)1 << 20;
    char* ws = (char*)d_ws;
    u16* xhi    = (u16*)(ws + 0 * MB);
    u16* xlo    = (u16*)(ws + 8 * MB);
    u16* WqkThi = (u16*)(ws + 16 * MB);
    u16* WqkTlo = (u16*)(ws + 20 * MB);
    u16* WvT    = (u16*)(ws + 24 * MB);
    u16* WoT    = (u16*)(ws + 26 * MB);
    u16* W1T    = (u16*)(ws + 32 * MB);
    u16* W2T    = (u16*)(ws + 40 * MB);
    u16* Qhi    = (u16*)(ws + 48 * MB);
    u16* Qlo    = (u16*)(ws + 56 * MB);
    u16* Khi    = (u16*)(ws + 64 * MB);
    u16* Klo    = (u16*)(ws + 72 * MB);
    u16* Vtb    = (u16*)(ws + 80 * MB);
    u16* aout   = (u16*)(ws + 16 * MB);
    float* O1   = (float*)(ws + 48 * MB);
    float* O2   = (float*)(ws + 64 * MB);
    u16* x1b    = (u16*)(ws + 80 * MB);
    u16* Hb     = (u16*)(ws + 0 * MB);
    float* H2a  = (float*)(ws + 48 * MB);
    float* H2b  = (float*)(ws + 64 * MB);

    split_f32<<<4096, 256, 0, stream>>>(x, xhi, xlo);
    transpose_split_f32<<<dim3(32, 32, 2), 256, 0, stream>>>(
        Wq, WqkThi, WqkTlo,
        Wk, WqkThi + 1024 * 1024, WqkTlo + 1024 * 1024, 1024, 1024);
    transpose_f32_bf16<<<dim3(32, 32, 2), 256, 0, stream>>>(Wv, WvT, Wo, WoT, 1024, 1024);
    transpose_f32_bf16<<<dim3(128, 32), 256, 0, stream>>>(W1, W1T, nullptr, nullptr, 1024, 4096);
    transpose_f32_bf16<<<dim3(32, 128), 256, 0, stream>>>(W2, W2T, nullptr, nullptr, 4096, 1024);

    gemm_qk_x3<<<dim3(16, 32), 512, 0, stream>>>(xhi, xlo, WqkThi, WqkTlo, bq, bk,
                                                 Qhi, Qlo, Khi, Klo);
    gemm_bt<<<dim3(8, 32), 512, 0, stream>>>(xhi, WvT, bv, 4096, 1024, 1024,
                                             MODE_VT, nullptr, Vtb, 0);

    attn_fwd<<<dim3(512), 512, 0, stream>>>(Qhi, Qlo, Khi, Klo, Vtb, aout);

    gemm_bt<<<dim3(8, 32, 2), 512, 0, stream>>>(aout, WoT, bo, 4096, 1024, 1024,
                                                MODE_F32, O1, nullptr, (size_t)16 * MB / 4);
    ln_res<<<1024, 256, 0, stream>>>(O1, O2, x, nullptr, g1, b1, x1b, nullptr);

    gemm_bt<<<dim3(32, 32), 512, 0, stream>>>(x1b, W1T, bm1, 4096, 4096, 1024,
                                              MODE_GELU, nullptr, Hb, 0);
    gemm_bt<<<dim3(8, 32, 2), 512, 0, stream>>>(Hb, W2T, bm2, 4096, 1024, 4096,
                                                MODE_F32, H2a, nullptr, (size_t)16 * MB / 4);
    ln_res<<<1024, 256, 0, stream>>>(H2a, H2b, nullptr, x1b, g2, b2, nullptr, (float*)d_out);
}